// Round 3
// baseline (1533.213 us; speedup 1.0000x reference)
//
#include <hip/hip_runtime.h>
#include <cmath>

#define T_TOK 4096
#define DM 1024
#define DFF 2816

typedef __bf16 bfx8 __attribute__((ext_vector_type(8)));
typedef float f32x4 __attribute__((ext_vector_type(4)));

__device__ __forceinline__ float bf2f(unsigned short u) {
    return __uint_as_float(((unsigned int)u) << 16);
}
__device__ __forceinline__ unsigned short f2bf(float f) {
    unsigned int b = __float_as_uint(f);
    return (unsigned short)((b + 0x7fffu + ((b >> 16) & 1u)) >> 16);
}
__device__ __forceinline__ uint4 pack8(const float* p) {
    float4 a = *(const float4*)p, b = *(const float4*)(p + 4);
    uint4 r;
    r.x = (unsigned)f2bf(a.x) | ((unsigned)f2bf(a.y) << 16);
    r.y = (unsigned)f2bf(a.z) | ((unsigned)f2bf(a.w) << 16);
    r.z = (unsigned)f2bf(b.x) | ((unsigned)f2bf(b.y) << 16);
    r.w = (unsigned)f2bf(b.z) | ((unsigned)f2bf(b.w) << 16);
    return r;
}
// async global->LDS, 16B per lane; LDS dest = wave-uniform base + lane*16
__device__ __forceinline__ void gld16(const unsigned short* g, unsigned short* l) {
    __builtin_amdgcn_global_load_lds((const __attribute__((address_space(1))) void*)g,
                                     (__attribute__((address_space(3))) void*)l, 16, 0, 0);
}

// ---------------- dtype probe + zero counters ----------------
__global__ void kProbe(const unsigned short* __restrict__ x, int* flag, int* counts, int* counts2) {
    __shared__ int cnt;
    if (threadIdx.x == 0) cnt = 0;
    __syncthreads();
    int sane = 0;
#pragma unroll
    for (int i = 0; i < 8; i++) {
        unsigned short u = x[threadIdx.x * 8 + i];
        int e = (u >> 7) & 0xFF;
        if (e >= 110 && e <= 134) sane++;
    }
    atomicAdd(&cnt, sane);
    __syncthreads();
    if (threadIdx.x == 0) flag[0] = (cnt >= 1843) ? 0 : 1;   // >=90% sane -> bf16
    if (threadIdx.x < 8) { counts[threadIdx.x] = 0; counts2[threadIdx.x] = 0; }
}

// ---------------- RMSNorm + gating (fp64, exact in both dtype modes) ----------------
__global__ __launch_bounds__(256) void kA(
    const void* __restrict__ xraw, const void* __restrict__ gwraw, const int* __restrict__ flag,
    float* __restrict__ accum, unsigned short* __restrict__ xnorm,
    int* __restrict__ counts, int* __restrict__ t2i, float* __restrict__ t2w)
{
    int f = flag[0];
    int t = blockIdx.x, tid = threadIdx.x;
    int wid = tid >> 6, lane = tid & 63;

    double xv[4]; double ss = 0.0;
    if (f) {
        const float* xr = (const float*)xraw + (size_t)t * DM;
#pragma unroll
        for (int i = 0; i < 4; i++) { xv[i] = (double)xr[tid + 256 * i]; ss += xv[i] * xv[i]; }
    } else {
        const unsigned short* xr = (const unsigned short*)xraw + (size_t)t * DM;
#pragma unroll
        for (int i = 0; i < 4; i++) { xv[i] = (double)bf2f(xr[tid + 256 * i]); ss += xv[i] * xv[i]; }
    }
#pragma unroll
    for (int o = 32; o > 0; o >>= 1) ss += __shfl_down(ss, o);

    __shared__ double sred[4];
    __shared__ double sscale;
    if (lane == 0) sred[wid] = ss;
    __syncthreads();
    if (tid == 0) {
        double tot = sred[0] + sred[1] + sred[2] + sred[3];
        sscale = 1.0 / sqrt(tot / (double)DM + 1e-6);
    }
    __syncthreads();
    double scale = sscale;

#pragma unroll
    for (int i = 0; i < 4; i++) {
        int idx = tid + 256 * i;
        accum[(size_t)t * DM + idx] = (float)xv[i];
        xnorm[(size_t)t * DM + idx] = f2bf((float)(xv[i] * scale));
    }

    const float* gw32 = (const float*)gwraw;
    const unsigned short* gw16 = (const unsigned short*)gwraw;
    double p[8];
#pragma unroll
    for (int e = 0; e < 8; e++) p[e] = 0.0;
#pragma unroll
    for (int i = 0; i < 4; i++) {
        int idx = tid + 256 * i;
#pragma unroll
        for (int e = 0; e < 8; e++) {
            double w = f ? (double)gw32[e * DM + idx] : (double)bf2f(gw16[e * DM + idx]);
            p[e] += xv[i] * w;
        }
    }
    __shared__ double gred[4][8];
#pragma unroll
    for (int e = 0; e < 8; e++) {
        double v = p[e];
#pragma unroll
        for (int o = 32; o > 0; o >>= 1) v += __shfl_down(v, o);
        if (lane == 0) gred[wid][e] = v;
    }
    __syncthreads();
    if (tid == 0) {
        double l[8], m = -1e300;
        for (int e = 0; e < 8; e++) {
            l[e] = scale * (gred[0][e] + gred[1][e] + gred[2][e] + gred[3][e]);
            if (l[e] > m) m = l[e];
        }
        double pe[8];
        for (int e = 0; e < 8; e++) pe[e] = exp(l[e] - m);
        int a = 0;
        for (int e = 1; e < 8; e++) if (pe[e] > pe[a]) a = e;
        int b = (a == 0) ? 1 : 0;
        for (int e = 0; e < 8; e++) { if (e == a) continue; if (pe[e] > pe[b]) b = e; }
        double s2 = pe[a] + pe[b];
        t2i[2 * t] = a; t2i[2 * t + 1] = b;
        t2w[2 * t] = (float)(pe[a] / s2); t2w[2 * t + 1] = (float)(pe[b] / s2);
        atomicAdd(&counts[a], 1); atomicAdd(&counts[b], 1);
    }
}

__global__ void kA2(const int* counts, int* base) {
    if (threadIdx.x == 0) {
        int acc = 0;
        for (int e = 0; e < 8; e++) { base[e] = acc; acc += counts[e]; }
    }
}

__global__ __launch_bounds__(256) void kA3(
    const int* __restrict__ t2i, const float* __restrict__ t2w, const int* __restrict__ base,
    int* counts2, int* __restrict__ rows_token, float* __restrict__ rows_w)
{
    int t = blockIdx.x * 256 + threadIdx.x;
    if (t < T_TOK) {
#pragma unroll
        for (int s = 0; s < 2; s++) {
            int e = t2i[2 * t + s];
            int pos = atomicAdd(&counts2[e], 1);
            int row = base[e] + pos;
            rows_token[row] = t; rows_w[row] = t2w[2 * t + s];
        }
        rows_token[2 * T_TOK + t] = t;
        rows_w[2 * T_TOK + t] = 1.0f;
    }
}

// ---------------- weight conversion fp32->bf16 (no-op in bf16 mode) ----------------
// w1b/w3b layout: [e(9)][row in chunk (CF)][DM]; grid (CF, 9), 256 thr (128 per array)
__global__ void kW13(const float* __restrict__ w1f, const float* __restrict__ w3f,
                     const float* __restrict__ sw1f, const float* __restrict__ sw3f,
                     const int* __restrict__ flag,
                     unsigned short* __restrict__ w1b, unsigned short* __restrict__ w3b,
                     int c0, int CF)
{
    if (flag[0] == 0) return;
    int row = blockIdx.x, e = blockIdx.y;
    int arr = threadIdx.x >> 7, kv = threadIdx.x & 127;
    const float* src;
    unsigned short* dst;
    if (arr == 0) {
        src = (e < 8) ? w1f + ((size_t)e * DFF + c0 + row) * DM : sw1f + (size_t)(c0 + row) * DM;
        dst = w1b + ((size_t)e * CF + row) * DM;
    } else {
        src = (e < 8) ? w3f + ((size_t)e * DFF + c0 + row) * DM : sw3f + (size_t)(c0 + row) * DM;
        dst = w3b + ((size_t)e * CF + row) * DM;
    }
    *(uint4*)&dst[kv * 8] = pack8(src + kv * 8);
}

// w2b layout: [e(9)][n (DM)][CF]; grid (DM, 9)
__global__ void kW2(const float* __restrict__ w2f, const float* __restrict__ sw2f,
                    const int* __restrict__ flag, unsigned short* __restrict__ w2b,
                    int c0, int CF)
{
    if (flag[0] == 0) return;
    int n = blockIdx.x, e = blockIdx.y;
    const float* src = ((e < 8) ? w2f + (size_t)e * DM * DFF : sw2f) + (size_t)n * DFF + c0;
    unsigned short* dst = w2b + ((size_t)e * DM + n) * CF;
    for (int rv = threadIdx.x; rv < CF / 8; rv += 256)
        *(uint4*)&dst[rv * 8] = pack8(src + rv * 8);
}

// ---------------- kB: dual GEMM (w1,w3) + GELU*mul -> h ----------------
// tile M=128 x N=64 (per weight), BK=64; global_load_lds staging; 4 waves 2x2
__global__ __launch_bounds__(256) void kB(
    const unsigned short* __restrict__ xnorm,
    const void* __restrict__ w1, const void* __restrict__ w3,
    const void* __restrict__ sw1, const void* __restrict__ sw3,
    const unsigned short* __restrict__ w1b, const unsigned short* __restrict__ w3b,
    const int* __restrict__ flag, const int* __restrict__ counts, const int* __restrict__ base,
    const int* __restrict__ rows_token, unsigned short* __restrict__ h, int c0, int CF)
{
    int e = blockIdx.z;
    int nr = (e < 8) ? counts[e] : T_TOK;
    int rb = (e < 8) ? base[e] : 2 * T_TOK;
    int r0 = blockIdx.x * 128;          // rows fastest -> consecutive blocks share B in L2
    if (r0 >= nr) return;
    int n0l = blockIdx.y * 64;
    int f = flag[0];

    __shared__ unsigned short sA[128 * 64];
    __shared__ unsigned short sB1[64 * 64];
    __shared__ unsigned short sB3[64 * 64];

    int tid = threadIdx.x, wid = tid >> 6, lane = tid & 63;
    int wr = wid >> 1, wc = wid & 1;
    int q = lane >> 4, ln = lane & 15;
    int lr = lane >> 3, lc = (lane & 7) * 8;

    // A staging: wave stages rows [wid*32, wid*32+32), 4 instrs x 8 rows
    const unsigned short* ga[4];
#pragma unroll
    for (int j = 0; j < 4; j++) {
        int r = r0 + wid * 32 + j * 8 + lr;
        int rc = (r < nr) ? r : (nr - 1);
        ga[j] = xnorm + (size_t)rows_token[rb + rc] * DM + lc;
    }
    // B staging: waves 0,1 -> sB1 rows [wid*32,+32); waves 2,3 -> sB3 rows [(wid-2)*32,+32)
    const unsigned short* gb[4];
    {
        bool isB3 = (wid >= 2);
        int whalf = wid & 1;
        const unsigned short* Wo = isB3
            ? ((e < 8) ? (const unsigned short*)w3 + (size_t)e * DFF * DM : (const unsigned short*)sw3)
            : ((e < 8) ? (const unsigned short*)w1 + (size_t)e * DFF * DM : (const unsigned short*)sw1);
        const unsigned short* Wb = (isB3 ? w3b : w1b) + (size_t)e * CF * DM;
#pragma unroll
        for (int j = 0; j < 4; j++) {
            int row = whalf * 32 + j * 8 + lr;
            gb[j] = f ? (Wb + (size_t)(n0l + row) * DM + lc)
                      : (Wo + (size_t)(c0 + n0l + row) * DM + lc);
        }
    }
    unsigned short* sBdst = (wid >= 2) ? sB3 : sB1;
    unsigned short* ldsA[4]; unsigned short* ldsB[4];
#pragma unroll
    for (int j = 0; j < 4; j++) {
        ldsA[j] = &sA[(wid * 32 + j * 8) * 64];
        ldsB[j] = &sBdst[((wid & 1) * 32 + j * 8) * 64];
    }

    f32x4 acc1[4][2], acc3[4][2];
#pragma unroll
    for (int m = 0; m < 4; m++)
#pragma unroll
        for (int n = 0; n < 2; n++) { acc1[m][n] = 0.0f; acc3[m][n] = 0.0f; }

    for (int ko = 0; ko < DM; ko += 64) {
#pragma unroll
        for (int j = 0; j < 4; j++) gld16(ga[j] + ko, ldsA[j]);
#pragma unroll
        for (int j = 0; j < 4; j++) gld16(gb[j] + ko, ldsB[j]);
        __syncthreads();
#pragma unroll
        for (int ks = 0; ks < 2; ks++) {
            bfx8 aF[4], b1F[2], b3F[2];
#pragma unroll
            for (int m = 0; m < 4; m++)
                aF[m] = *(const bfx8*)&sA[(wr * 64 + m * 16 + ln) * 64 + ks * 32 + q * 8];
#pragma unroll
            for (int n = 0; n < 2; n++) {
                b1F[n] = *(const bfx8*)&sB1[(wc * 32 + n * 16 + ln) * 64 + ks * 32 + q * 8];
                b3F[n] = *(const bfx8*)&sB3[(wc * 32 + n * 16 + ln) * 64 + ks * 32 + q * 8];
            }
#pragma unroll
            for (int m = 0; m < 4; m++)
#pragma unroll
                for (int n = 0; n < 2; n++) {
                    acc1[m][n] = __builtin_amdgcn_mfma_f32_16x16x32_bf16(aF[m], b1F[n], acc1[m][n], 0, 0, 0);
                    acc3[m][n] = __builtin_amdgcn_mfma_f32_16x16x32_bf16(aF[m], b3F[n], acc3[m][n], 0, 0, 0);
                }
        }
        __syncthreads();
    }

#pragma unroll
    for (int m = 0; m < 4; m++)
#pragma unroll
        for (int r = 0; r < 4; r++) {
            int gr = r0 + wr * 64 + m * 16 + q * 4 + r;
            if (gr < nr) {
#pragma unroll
                for (int n = 0; n < 2; n++) {
                    float a = acc1[m][n][r], b3v = acc3[m][n][r];
                    float g = 0.5f * a * (1.0f + erff(a * 0.70710678118654752f));
                    h[(size_t)(rb + gr) * CF + n0l + wc * 32 + n * 16 + ln] = f2bf(g * b3v);
                }
            }
        }
}

// ---------------- kC: h @ w2^T (k-chunk), scale, atomic accumulate ----------------
// tile M=128 x N=128, BK=64
__global__ __launch_bounds__(256) void kC(
    const unsigned short* __restrict__ h,
    const void* __restrict__ w2, const void* __restrict__ sw2,
    const unsigned short* __restrict__ w2b,
    const int* __restrict__ flag, const int* __restrict__ counts, const int* __restrict__ base,
    const int* __restrict__ rows_token, const float* __restrict__ rows_w,
    float* __restrict__ accum, int c0, int CF)
{
    int e = blockIdx.z;
    int nr = (e < 8) ? counts[e] : T_TOK;
    int rb = (e < 8) ? base[e] : 2 * T_TOK;
    int r0 = blockIdx.x * 128;
    if (r0 >= nr) return;
    int n0 = blockIdx.y * 128;
    int f = flag[0];

    __shared__ unsigned short sA[128 * 64];
    __shared__ unsigned short sB[128 * 64];

    int tid = threadIdx.x, wid = tid >> 6, lane = tid & 63;
    int wr = wid >> 1, wc = wid & 1;
    int q = lane >> 4, ln = lane & 15;
    int lr = lane >> 3, lc = (lane & 7) * 8;

    const unsigned short* Wo = (e < 8) ? (const unsigned short*)w2 + (size_t)e * DM * DFF
                                       : (const unsigned short*)sw2;
    const unsigned short* Wb = w2b + (size_t)e * DM * CF;
    const unsigned short* ga[4]; const unsigned short* gb[4];
#pragma unroll
    for (int j = 0; j < 4; j++) {
        int r = r0 + wid * 32 + j * 8 + lr;            // h rows are compact; reads stay in-bounds
        ga[j] = h + (size_t)(rb + r) * CF + lc;
        int n = n0 + wid * 32 + j * 8 + lr;
        gb[j] = f ? (Wb + (size_t)n * CF + lc) : (Wo + (size_t)n * DFF + c0 + lc);
    }
    unsigned short* ldsA[4]; unsigned short* ldsB[4];
#pragma unroll
    for (int j = 0; j < 4; j++) {
        ldsA[j] = &sA[(wid * 32 + j * 8) * 64];
        ldsB[j] = &sB[(wid * 32 + j * 8) * 64];
    }

    f32x4 acc[4][4];
#pragma unroll
    for (int m = 0; m < 4; m++)
#pragma unroll
        for (int n = 0; n < 4; n++) acc[m][n] = 0.0f;

    for (int ko = 0; ko < CF; ko += 64) {
#pragma unroll
        for (int j = 0; j < 4; j++) gld16(ga[j] + ko, ldsA[j]);
#pragma unroll
        for (int j = 0; j < 4; j++) gld16(gb[j] + ko, ldsB[j]);
        __syncthreads();
#pragma unroll
        for (int ks = 0; ks < 2; ks++) {
            bfx8 aF[4], bF[4];
#pragma unroll
            for (int m = 0; m < 4; m++)
                aF[m] = *(const bfx8*)&sA[(wr * 64 + m * 16 + ln) * 64 + ks * 32 + q * 8];
#pragma unroll
            for (int n = 0; n < 4; n++)
                bF[n] = *(const bfx8*)&sB[(wc * 64 + n * 16 + ln) * 64 + ks * 32 + q * 8];
#pragma unroll
            for (int m = 0; m < 4; m++)
#pragma unroll
                for (int n = 0; n < 4; n++)
                    acc[m][n] = __builtin_amdgcn_mfma_f32_16x16x32_bf16(aF[m], bF[n], acc[m][n], 0, 0, 0);
        }
        __syncthreads();
    }

#pragma unroll
    for (int m = 0; m < 4; m++)
#pragma unroll
        for (int r = 0; r < 4; r++) {
            int gr = r0 + wr * 64 + m * 16 + q * 4 + r;
            if (gr < nr) {
                float w = rows_w[rb + gr];
                int tk = rows_token[rb + gr];
#pragma unroll
                for (int n = 0; n < 4; n++)
                    atomicAdd(&accum[(size_t)tk * DM + n0 + wc * 64 + n * 16 + ln], acc[m][n][r] * w);
            }
        }
}

// ---------------- fp32 accum -> out (dtype per flag) ----------------
__global__ __launch_bounds__(256) void kD(const float* __restrict__ accum, void* __restrict__ outraw,
                                          const int* __restrict__ flag) {
    int f = flag[0];
    int i = (blockIdx.x * 256 + threadIdx.x) * 4;
    float4 v = *(const float4*)&accum[i];
    if (f) {
        *(float4*)((float*)outraw + i) = v;
    } else {
        ushort4 u;
        u.x = f2bf(v.x); u.y = f2bf(v.y); u.z = f2bf(v.z); u.w = f2bf(v.w);
        *(ushort4*)((unsigned short*)outraw + i) = u;
    }
}

extern "C" void kernel_launch(void* const* d_in, const int* in_sizes, int n_in,
                              void* d_out, int out_size, void* d_ws, size_t ws_size,
                              hipStream_t stream)
{
    const void* x   = d_in[0];
    const void* gw  = d_in[1];
    const void* w1  = d_in[2];
    const void* w2  = d_in[3];
    const void* w3  = d_in[4];
    const void* sw1 = d_in[5];
    const void* sw2 = d_in[6];
    const void* sw3 = d_in[7];

    char* ws = (char*)d_ws;
    size_t off = 0;
    auto alloc = [&](size_t bytes) { void* p = ws + off; off += (bytes + 255) & ~(size_t)255; return p; };
    int* flag             = (int*)alloc(256);
    unsigned short* xnorm = (unsigned short*)alloc((size_t)T_TOK * DM * 2);
    float* accum          = (float*)alloc((size_t)T_TOK * DM * 4);
    int* counts           = (int*)alloc(256);
    int* counts2          = (int*)alloc(256);
    int* base             = (int*)alloc(256);
    int* rows_token       = (int*)alloc((size_t)3 * T_TOK * 4);
    float* rows_w         = (float*)alloc((size_t)3 * T_TOK * 4);
    int* t2i              = (int*)alloc((size_t)T_TOK * 2 * 4);
    float* t2w            = (float*)alloc((size_t)T_TOK * 2 * 4);

    // per-chunk buffers: w1b+w3b+w2b slices (9 experts each) + h; CF must be /64
    static const int ncs[6] = {1, 2, 4, 11, 22, 44};
    int NC = 44;
    for (int i = 0; i < 6; i++) {
        size_t CFi = DFF / ncs[i];
        size_t need = off + CFi * ((size_t)9 * DM * 2 * 3 + (size_t)3 * T_TOK * 2) + 1024;
        if (need <= ws_size) { NC = ncs[i]; break; }
    }
    int CF = DFF / NC;
    unsigned short* w1b = (unsigned short*)alloc((size_t)9 * CF * DM * 2);
    unsigned short* w3b = (unsigned short*)alloc((size_t)9 * CF * DM * 2);
    unsigned short* w2b = (unsigned short*)alloc((size_t)9 * DM * CF * 2);
    unsigned short* h   = (unsigned short*)alloc((size_t)3 * T_TOK * CF * 2);

    kProbe<<<1, 256, 0, stream>>>((const unsigned short*)x, flag, counts, counts2);
    kA<<<T_TOK, 256, 0, stream>>>(x, gw, flag, accum, xnorm, counts, t2i, t2w);
    kA2<<<1, 64, 0, stream>>>(counts, base);
    kA3<<<(T_TOK + 255) / 256, 256, 0, stream>>>(t2i, t2w, base, counts2, rows_token, rows_w);
    for (int c = 0; c < NC; c++) {
        int c0 = c * CF;
        kW13<<<dim3(CF, 9), 256, 0, stream>>>((const float*)w1, (const float*)w3,
                                              (const float*)sw1, (const float*)sw3,
                                              flag, w1b, w3b, c0, CF);
        kW2<<<dim3(DM, 9), 256, 0, stream>>>((const float*)w2, (const float*)sw2, flag, w2b, c0, CF);
        kB<<<dim3(32, CF / 64, 9), 256, 0, stream>>>(xnorm, w1, w3, sw1, sw3, w1b, w3b,
                                                     flag, counts, base, rows_token, h, c0, CF);
        kC<<<dim3(32, 8, 9), 256, 0, stream>>>(h, w2, sw2, w2b, flag, counts, base,
                                               rows_token, rows_w, accum, c0, CF);
    }
    kD<<<(T_TOK * DM) / 1024, 256, 0, stream>>>(accum, d_out, flag);
}

// Round 4
// 1326.067 us; speedup vs baseline: 1.1562x; 1.1562x over previous
//
#include <hip/hip_runtime.h>
#include <cmath>

#define T_TOK 4096
#define DM 1024
#define DFF 2816

typedef __bf16 bfx8 __attribute__((ext_vector_type(8)));
typedef float f32x4 __attribute__((ext_vector_type(4)));

__device__ __forceinline__ float bf2f(unsigned short u) {
    return __uint_as_float(((unsigned int)u) << 16);
}
__device__ __forceinline__ unsigned short f2bf(float f) {
    unsigned int b = __float_as_uint(f);
    return (unsigned short)((b + 0x7fffu + ((b >> 16) & 1u)) >> 16);
}
__device__ __forceinline__ uint4 pack8(const float* p) {
    float4 a = *(const float4*)p, b = *(const float4*)(p + 4);
    uint4 r;
    r.x = (unsigned)f2bf(a.x) | ((unsigned)f2bf(a.y) << 16);
    r.y = (unsigned)f2bf(a.z) | ((unsigned)f2bf(a.w) << 16);
    r.z = (unsigned)f2bf(b.x) | ((unsigned)f2bf(b.y) << 16);
    r.w = (unsigned)f2bf(b.z) | ((unsigned)f2bf(b.w) << 16);
    return r;
}
// async global->LDS, 16B/lane; LDS dest = wave-uniform base + lane*16 (HW-fixed)
__device__ __forceinline__ void gld16(const unsigned short* g, unsigned short* l) {
    __builtin_amdgcn_global_load_lds((const __attribute__((address_space(1))) void*)g,
                                     (__attribute__((address_space(3))) void*)l, 16, 0, 0);
}
// XOR-swizzle: lane fetches global chunk (ch ^ lr) so LDS[r][c] = G[r][c^(r&7)]
// staging column offset (elements) for this lane within a 64-elem K-window
__device__ __forceinline__ int stg_col(int lane) {
    return ((lane & 7) ^ (lane >> 3)) * 8;
}
// LDS element offset for row r, 8-elem chunk c (c = ks*4+q), 64-elem rows
__device__ __forceinline__ int lds_off(int r, int c) {
    return r * 64 + ((c ^ (r & 7)) * 8);
}

// ---------------- dtype probe + zero counters ----------------
__global__ void kProbe(const unsigned short* __restrict__ x, int* flag, int* counts, int* counts2) {
    __shared__ int cnt;
    if (threadIdx.x == 0) cnt = 0;
    __syncthreads();
    int sane = 0;
#pragma unroll
    for (int i = 0; i < 8; i++) {
        unsigned short u = x[threadIdx.x * 8 + i];
        int e = (u >> 7) & 0xFF;
        if (e >= 110 && e <= 134) sane++;
    }
    atomicAdd(&cnt, sane);
    __syncthreads();
    if (threadIdx.x == 0) flag[0] = (cnt >= 1843) ? 0 : 1;   // >=90% sane -> bf16
    if (threadIdx.x < 8) { counts[threadIdx.x] = 0; counts2[threadIdx.x] = 0; }
}

// ---------------- RMSNorm + gating (fp64, exact in both dtype modes) ----------------
__global__ __launch_bounds__(256) void kA(
    const void* __restrict__ xraw, const void* __restrict__ gwraw, const int* __restrict__ flag,
    float* __restrict__ accum, unsigned short* __restrict__ xnorm,
    int* __restrict__ counts, int* __restrict__ t2i, float* __restrict__ t2w)
{
    int f = flag[0];
    int t = blockIdx.x, tid = threadIdx.x;
    int wid = tid >> 6, lane = tid & 63;

    double xv[4]; double ss = 0.0;
    if (f) {
        const float* xr = (const float*)xraw + (size_t)t * DM;
#pragma unroll
        for (int i = 0; i < 4; i++) { xv[i] = (double)xr[tid + 256 * i]; ss += xv[i] * xv[i]; }
    } else {
        const unsigned short* xr = (const unsigned short*)xraw + (size_t)t * DM;
#pragma unroll
        for (int i = 0; i < 4; i++) { xv[i] = (double)bf2f(xr[tid + 256 * i]); ss += xv[i] * xv[i]; }
    }
#pragma unroll
    for (int o = 32; o > 0; o >>= 1) ss += __shfl_down(ss, o);

    __shared__ double sred[4];
    __shared__ double sscale;
    if (lane == 0) sred[wid] = ss;
    __syncthreads();
    if (tid == 0) {
        double tot = sred[0] + sred[1] + sred[2] + sred[3];
        sscale = 1.0 / sqrt(tot / (double)DM + 1e-6);
    }
    __syncthreads();
    double scale = sscale;

#pragma unroll
    for (int i = 0; i < 4; i++) {
        int idx = tid + 256 * i;
        accum[(size_t)t * DM + idx] = (float)xv[i];
        xnorm[(size_t)t * DM + idx] = f2bf((float)(xv[i] * scale));
    }

    const float* gw32 = (const float*)gwraw;
    const unsigned short* gw16 = (const unsigned short*)gwraw;
    double p[8];
#pragma unroll
    for (int e = 0; e < 8; e++) p[e] = 0.0;
#pragma unroll
    for (int i = 0; i < 4; i++) {
        int idx = tid + 256 * i;
#pragma unroll
        for (int e = 0; e < 8; e++) {
            double w = f ? (double)gw32[e * DM + idx] : (double)bf2f(gw16[e * DM + idx]);
            p[e] += xv[i] * w;
        }
    }
    __shared__ double gred[4][8];
#pragma unroll
    for (int e = 0; e < 8; e++) {
        double v = p[e];
#pragma unroll
        for (int o = 32; o > 0; o >>= 1) v += __shfl_down(v, o);
        if (lane == 0) gred[wid][e] = v;
    }
    __syncthreads();
    if (tid == 0) {
        double l[8], m = -1e300;
        for (int e = 0; e < 8; e++) {
            l[e] = scale * (gred[0][e] + gred[1][e] + gred[2][e] + gred[3][e]);
            if (l[e] > m) m = l[e];
        }
        double pe[8];
        for (int e = 0; e < 8; e++) pe[e] = exp(l[e] - m);
        int a = 0;
        for (int e = 1; e < 8; e++) if (pe[e] > pe[a]) a = e;
        int b = (a == 0) ? 1 : 0;
        for (int e = 0; e < 8; e++) { if (e == a) continue; if (pe[e] > pe[b]) b = e; }
        double s2 = pe[a] + pe[b];
        t2i[2 * t] = a; t2i[2 * t + 1] = b;
        t2w[2 * t] = (float)(pe[a] / s2); t2w[2 * t + 1] = (float)(pe[b] / s2);
        atomicAdd(&counts[a], 1); atomicAdd(&counts[b], 1);
    }
}

__global__ void kA2(const int* counts, int* base) {
    if (threadIdx.x == 0) {
        int acc = 0;
        for (int e = 0; e < 8; e++) { base[e] = acc; acc += counts[e]; }
    }
}

__global__ __launch_bounds__(256) void kA3(
    const int* __restrict__ t2i, const float* __restrict__ t2w, const int* __restrict__ base,
    int* counts2, int* __restrict__ rows_token, float* __restrict__ rows_w)
{
    int t = blockIdx.x * 256 + threadIdx.x;
    if (t < T_TOK) {
#pragma unroll
        for (int s = 0; s < 2; s++) {
            int e = t2i[2 * t + s];
            int pos = atomicAdd(&counts2[e], 1);
            int row = base[e] + pos;
            rows_token[row] = t; rows_w[row] = t2w[2 * t + s];
        }
        rows_token[2 * T_TOK + t] = t;
        rows_w[2 * T_TOK + t] = 1.0f;
    }
}

// ---------------- weight conversion fp32->bf16 (no-op in bf16 mode) ----------------
__global__ void kW13(const float* __restrict__ w1f, const float* __restrict__ w3f,
                     const float* __restrict__ sw1f, const float* __restrict__ sw3f,
                     const int* __restrict__ flag,
                     unsigned short* __restrict__ w1b, unsigned short* __restrict__ w3b,
                     int c0, int CF)
{
    if (flag[0] == 0) return;
    int row = blockIdx.x, e = blockIdx.y;
    int arr = threadIdx.x >> 7, kv = threadIdx.x & 127;
    const float* src;
    unsigned short* dst;
    if (arr == 0) {
        src = (e < 8) ? w1f + ((size_t)e * DFF + c0 + row) * DM : sw1f + (size_t)(c0 + row) * DM;
        dst = w1b + ((size_t)e * CF + row) * DM;
    } else {
        src = (e < 8) ? w3f + ((size_t)e * DFF + c0 + row) * DM : sw3f + (size_t)(c0 + row) * DM;
        dst = w3b + ((size_t)e * CF + row) * DM;
    }
    *(uint4*)&dst[kv * 8] = pack8(src + kv * 8);
}

__global__ void kW2(const float* __restrict__ w2f, const float* __restrict__ sw2f,
                    const int* __restrict__ flag, unsigned short* __restrict__ w2b,
                    int c0, int CF)
{
    if (flag[0] == 0) return;
    int n = blockIdx.x, e = blockIdx.y;
    const float* src = ((e < 8) ? w2f + (size_t)e * DM * DFF : sw2f) + (size_t)n * DFF + c0;
    unsigned short* dst = w2b + ((size_t)e * DM + n) * CF;
    for (int rv = threadIdx.x; rv < CF / 8; rv += 256)
        *(uint4*)&dst[rv * 8] = pack8(src + rv * 8);
}

// ---------------- kB: dual GEMM (w1,w3) + GELU*mul -> h ----------------
// tile M=128 x N=64 (per weight), BK=64; global_load_lds + XOR-swizzled LDS
__global__ __launch_bounds__(256) void kB(
    const unsigned short* __restrict__ xnorm,
    const void* __restrict__ w1, const void* __restrict__ w3,
    const void* __restrict__ sw1, const void* __restrict__ sw3,
    const unsigned short* __restrict__ w1b, const unsigned short* __restrict__ w3b,
    const int* __restrict__ flag, const int* __restrict__ counts, const int* __restrict__ base,
    const int* __restrict__ rows_token, unsigned short* __restrict__ h, int c0, int CF)
{
    int e = blockIdx.z;
    int nr = (e < 8) ? counts[e] : T_TOK;
    int rb = (e < 8) ? base[e] : 2 * T_TOK;
    int r0 = blockIdx.x * 128;          // rows fastest -> consecutive blocks share B in L2
    if (r0 >= nr) return;
    int n0l = blockIdx.y * 64;
    int f = flag[0];

    __shared__ unsigned short sA[128 * 64];
    __shared__ unsigned short sB1[64 * 64];
    __shared__ unsigned short sB3[64 * 64];

    int tid = threadIdx.x, wid = tid >> 6, lane = tid & 63;
    int wr = wid >> 1, wc = wid & 1;
    int q = lane >> 4, ln = lane & 15;
    int lr = lane >> 3;                 // row within 8-row staging group
    int lc = stg_col(lane);             // swizzled source column (elements)

    const unsigned short* ga[4];
#pragma unroll
    for (int j = 0; j < 4; j++) {
        int r = r0 + wid * 32 + j * 8 + lr;
        int rc = (r < nr) ? r : (nr - 1);
        ga[j] = xnorm + (size_t)rows_token[rb + rc] * DM + lc;
    }
    const unsigned short* gb[4];
    {
        bool isB3 = (wid >= 2);
        int whalf = wid & 1;
        const unsigned short* Wo = isB3
            ? ((e < 8) ? (const unsigned short*)w3 + (size_t)e * DFF * DM : (const unsigned short*)sw3)
            : ((e < 8) ? (const unsigned short*)w1 + (size_t)e * DFF * DM : (const unsigned short*)sw1);
        const unsigned short* Wb = (isB3 ? w3b : w1b) + (size_t)e * CF * DM;
#pragma unroll
        for (int j = 0; j < 4; j++) {
            int row = whalf * 32 + j * 8 + lr;
            gb[j] = f ? (Wb + (size_t)(n0l + row) * DM + lc)
                      : (Wo + (size_t)(c0 + n0l + row) * DM + lc);
        }
    }
    unsigned short* sBdst = (wid >= 2) ? sB3 : sB1;
    unsigned short* ldsA[4]; unsigned short* ldsB[4];
#pragma unroll
    for (int j = 0; j < 4; j++) {
        ldsA[j] = &sA[(wid * 32 + j * 8) * 64];
        ldsB[j] = &sBdst[((wid & 1) * 32 + j * 8) * 64];
    }

    f32x4 acc1[4][2], acc3[4][2];
#pragma unroll
    for (int m = 0; m < 4; m++)
#pragma unroll
        for (int n = 0; n < 2; n++) { acc1[m][n] = 0.0f; acc3[m][n] = 0.0f; }

    for (int ko = 0; ko < DM; ko += 64) {
#pragma unroll
        for (int j = 0; j < 4; j++) gld16(ga[j] + ko, ldsA[j]);
#pragma unroll
        for (int j = 0; j < 4; j++) gld16(gb[j] + ko, ldsB[j]);
        __syncthreads();
#pragma unroll
        for (int ks = 0; ks < 2; ks++) {
            bfx8 aF[4], b1F[2], b3F[2];
#pragma unroll
            for (int m = 0; m < 4; m++)
                aF[m] = *(const bfx8*)&sA[lds_off(wr * 64 + m * 16 + ln, ks * 4 + q)];
#pragma unroll
            for (int n = 0; n < 2; n++) {
                int rbn = wc * 32 + n * 16 + ln;
                b1F[n] = *(const bfx8*)&sB1[lds_off(rbn, ks * 4 + q)];
                b3F[n] = *(const bfx8*)&sB3[lds_off(rbn, ks * 4 + q)];
            }
#pragma unroll
            for (int m = 0; m < 4; m++)
#pragma unroll
                for (int n = 0; n < 2; n++) {
                    acc1[m][n] = __builtin_amdgcn_mfma_f32_16x16x32_bf16(aF[m], b1F[n], acc1[m][n], 0, 0, 0);
                    acc3[m][n] = __builtin_amdgcn_mfma_f32_16x16x32_bf16(aF[m], b3F[n], acc3[m][n], 0, 0, 0);
                }
        }
        __syncthreads();
    }

#pragma unroll
    for (int m = 0; m < 4; m++)
#pragma unroll
        for (int r = 0; r < 4; r++) {
            int gr = r0 + wr * 64 + m * 16 + q * 4 + r;
            if (gr < nr) {
#pragma unroll
                for (int n = 0; n < 2; n++) {
                    float a = acc1[m][n][r], b3v = acc3[m][n][r];
                    float g = 0.5f * a * (1.0f + erff(a * 0.70710678118654752f));
                    h[(size_t)(rb + gr) * CF + n0l + wc * 32 + n * 16 + ln] = f2bf(g * b3v);
                }
            }
        }
}

// ---------------- kC: h @ w2^T (k-chunk), scale, atomic accumulate ----------------
// tile M=128 x N=128, BK=64; global_load_lds + XOR-swizzled LDS
__global__ __launch_bounds__(256) void kC(
    const unsigned short* __restrict__ h,
    const void* __restrict__ w2, const void* __restrict__ sw2,
    const unsigned short* __restrict__ w2b,
    const int* __restrict__ flag, const int* __restrict__ counts, const int* __restrict__ base,
    const int* __restrict__ rows_token, const float* __restrict__ rows_w,
    float* __restrict__ accum, int c0, int CF)
{
    int e = blockIdx.z;
    int nr = (e < 8) ? counts[e] : T_TOK;
    int rb = (e < 8) ? base[e] : 2 * T_TOK;
    int r0 = blockIdx.x * 128;
    if (r0 >= nr) return;
    int n0 = blockIdx.y * 128;
    int f = flag[0];

    __shared__ unsigned short sA[128 * 64];
    __shared__ unsigned short sB[128 * 64];

    int tid = threadIdx.x, wid = tid >> 6, lane = tid & 63;
    int wr = wid >> 1, wc = wid & 1;
    int q = lane >> 4, ln = lane & 15;
    int lr = lane >> 3;
    int lc = stg_col(lane);

    const unsigned short* Wo = (e < 8) ? (const unsigned short*)w2 + (size_t)e * DM * DFF
                                       : (const unsigned short*)sw2;
    const unsigned short* Wb = w2b + (size_t)e * DM * CF;
    const unsigned short* ga[4]; const unsigned short* gb[4];
#pragma unroll
    for (int j = 0; j < 4; j++) {
        int r = r0 + wid * 32 + j * 8 + lr;            // h rows compact; stays in-buffer
        ga[j] = h + (size_t)(rb + r) * CF + lc;
        int n = n0 + wid * 32 + j * 8 + lr;
        gb[j] = f ? (Wb + (size_t)n * CF + lc) : (Wo + (size_t)n * DFF + c0 + lc);
    }
    unsigned short* ldsA[4]; unsigned short* ldsB[4];
#pragma unroll
    for (int j = 0; j < 4; j++) {
        ldsA[j] = &sA[(wid * 32 + j * 8) * 64];
        ldsB[j] = &sB[(wid * 32 + j * 8) * 64];
    }

    f32x4 acc[4][4];
#pragma unroll
    for (int m = 0; m < 4; m++)
#pragma unroll
        for (int n = 0; n < 4; n++) acc[m][n] = 0.0f;

    for (int ko = 0; ko < CF; ko += 64) {
#pragma unroll
        for (int j = 0; j < 4; j++) gld16(ga[j] + ko, ldsA[j]);
#pragma unroll
        for (int j = 0; j < 4; j++) gld16(gb[j] + ko, ldsB[j]);
        __syncthreads();
#pragma unroll
        for (int ks = 0; ks < 2; ks++) {
            bfx8 aF[4], bF[4];
#pragma unroll
            for (int m = 0; m < 4; m++)
                aF[m] = *(const bfx8*)&sA[lds_off(wr * 64 + m * 16 + ln, ks * 4 + q)];
#pragma unroll
            for (int n = 0; n < 4; n++)
                bF[n] = *(const bfx8*)&sB[lds_off(wc * 64 + n * 16 + ln, ks * 4 + q)];
#pragma unroll
            for (int m = 0; m < 4; m++)
#pragma unroll
                for (int n = 0; n < 4; n++)
                    acc[m][n] = __builtin_amdgcn_mfma_f32_16x16x32_bf16(aF[m], bF[n], acc[m][n], 0, 0, 0);
        }
        __syncthreads();
    }

#pragma unroll
    for (int m = 0; m < 4; m++)
#pragma unroll
        for (int r = 0; r < 4; r++) {
            int gr = r0 + wr * 64 + m * 16 + q * 4 + r;
            if (gr < nr) {
                float w = rows_w[rb + gr];
                int tk = rows_token[rb + gr];
#pragma unroll
                for (int n = 0; n < 4; n++)
                    atomicAdd(&accum[(size_t)tk * DM + n0 + wc * 64 + n * 16 + ln], acc[m][n][r] * w);
            }
        }
}

// ---------------- fp32 accum -> out (dtype per flag) ----------------
__global__ __launch_bounds__(256) void kD(const float* __restrict__ accum, void* __restrict__ outraw,
                                          const int* __restrict__ flag) {
    int f = flag[0];
    int i = (blockIdx.x * 256 + threadIdx.x) * 4;
    float4 v = *(const float4*)&accum[i];
    if (f) {
        *(float4*)((float*)outraw + i) = v;
    } else {
        ushort4 u;
        u.x = f2bf(v.x); u.y = f2bf(v.y); u.z = f2bf(v.z); u.w = f2bf(v.w);
        *(ushort4*)((unsigned short*)outraw + i) = u;
    }
}

extern "C" void kernel_launch(void* const* d_in, const int* in_sizes, int n_in,
                              void* d_out, int out_size, void* d_ws, size_t ws_size,
                              hipStream_t stream)
{
    const void* x   = d_in[0];
    const void* gw  = d_in[1];
    const void* w1  = d_in[2];
    const void* w2  = d_in[3];
    const void* w3  = d_in[4];
    const void* sw1 = d_in[5];
    const void* sw2 = d_in[6];
    const void* sw3 = d_in[7];

    char* ws = (char*)d_ws;
    size_t off = 0;
    auto alloc = [&](size_t bytes) { void* p = ws + off; off += (bytes + 255) & ~(size_t)255; return p; };
    int* flag             = (int*)alloc(256);
    unsigned short* xnorm = (unsigned short*)alloc((size_t)T_TOK * DM * 2);
    float* accum          = (float*)alloc((size_t)T_TOK * DM * 4);
    int* counts           = (int*)alloc(256);
    int* counts2          = (int*)alloc(256);
    int* base             = (int*)alloc(256);
    int* rows_token       = (int*)alloc((size_t)3 * T_TOK * 4);
    float* rows_w         = (float*)alloc((size_t)3 * T_TOK * 4);
    int* t2i              = (int*)alloc((size_t)T_TOK * 2 * 4);
    float* t2w            = (float*)alloc((size_t)T_TOK * 2 * 4);

    static const int ncs[6] = {1, 2, 4, 11, 22, 44};
    int NC = 44;
    for (int i = 0; i < 6; i++) {
        size_t CFi = DFF / ncs[i];
        size_t need = off + CFi * ((size_t)9 * DM * 2 * 3 + (size_t)3 * T_TOK * 2) + 1024;
        if (need <= ws_size) { NC = ncs[i]; break; }
    }
    int CF = DFF / NC;
    unsigned short* w1b = (unsigned short*)alloc((size_t)9 * CF * DM * 2);
    unsigned short* w3b = (unsigned short*)alloc((size_t)9 * CF * DM * 2);
    unsigned short* w2b = (unsigned short*)alloc((size_t)9 * DM * CF * 2);
    unsigned short* h   = (unsigned short*)alloc((size_t)3 * T_TOK * CF * 2);

    kProbe<<<1, 256, 0, stream>>>((const unsigned short*)x, flag, counts, counts2);
    kA<<<T_TOK, 256, 0, stream>>>(x, gw, flag, accum, xnorm, counts, t2i, t2w);
    kA2<<<1, 64, 0, stream>>>(counts, base);
    kA3<<<(T_TOK + 255) / 256, 256, 0, stream>>>(t2i, t2w, base, counts2, rows_token, rows_w);
    for (int c = 0; c < NC; c++) {
        int c0 = c * CF;
        kW13<<<dim3(CF, 9), 256, 0, stream>>>((const float*)w1, (const float*)w3,
                                              (const float*)sw1, (const float*)sw3,
                                              flag, w1b, w3b, c0, CF);
        kW2<<<dim3(DM, 9), 256, 0, stream>>>((const float*)w2, (const float*)sw2, flag, w2b, c0, CF);
        kB<<<dim3(32, CF / 64, 9), 256, 0, stream>>>(xnorm, w1, w3, sw1, sw3, w1b, w3b,
                                                     flag, counts, base, rows_token, h, c0, CF);
        kC<<<dim3(32, 8, 9), 256, 0, stream>>>(h, w2, sw2, w2b, flag, counts, base,
                                               rows_token, rows_w, accum, c0, CF);
    }
    kD<<<(T_TOK * DM) / 1024, 256, 0, stream>>>(accum, d_out, flag);
}